// Round 9
// baseline (79.842 us; speedup 1.0000x reference)
//
#include <hip/hip_runtime.h>
#include <hip/hip_bf16.h>
#include <stdint.h>

// B=8, T=1024, D=U=640, H=10, d=64
#define B_DIM 8
#define T_DIM 1024
#define D_DIM 640
#define H_DIM 10
#define LOG2E 1.442695041f

typedef unsigned short ushort_t;
typedef __attribute__((ext_vector_type(8))) short short8;
typedef __attribute__((ext_vector_type(4))) float f32x4;
typedef __attribute__((ext_vector_type(16))) float f32x16;
typedef __attribute__((ext_vector_type(4))) unsigned int u32x4;

__device__ __forceinline__ ushort_t f32_to_bf16(float f) {
    unsigned int u = __builtin_bit_cast(unsigned int, f);
    u += 0x7fffu + ((u >> 16) & 1u);   // RNE
    return (ushort_t)(u >> 16);
}
__device__ __forceinline__ float v_exp2(float x) {
    float r; asm("v_exp_f32 %0, %1" : "=v"(r) : "v"(x)); return r;
}
__device__ __forceinline__ unsigned cvt_pk_bf16(float a, float b) {
    unsigned r; asm("v_cvt_pk_bf16_f32 %0, %1, %2" : "=v"(r) : "v"(a), "v"(b)); return r;
}
// async global->LDS (GEMM staging only)
__device__ __forceinline__ void gload16(const void* g, void* l) {
    auto gp = reinterpret_cast<const __attribute__((address_space(1))) uint32_t*>(
        reinterpret_cast<uintptr_t>(g));
    auto lp = reinterpret_cast<__attribute__((address_space(3))) uint32_t*>(
        reinterpret_cast<uintptr_t>(l));
    __builtin_amdgcn_global_load_lds(gp, lp, 16, 0, 0);
}

// strips sorted heavy-first by tile count: 0(16),31(16),30(16),29(15),...
__constant__ int SPERM[32] = {0,31,30,29,28,27,26,25,24,23,22,21,20,19,18,17,
                              16,15,14,13,12,11,10,9,8,7,6,5,4,3,2,1};

// ---------------------------------------------------------------------------
// Kernel A: fused { W transpose->bf16 (blocks 0..299) , x->bf16 (blocks 300+) }
// ---------------------------------------------------------------------------
__global__ __launch_bounds__(256) void convwt(
    const float* __restrict__ x,
    const float* __restrict__ Wq, const float* __restrict__ Wk, const float* __restrict__ Wv,
    ushort_t* __restrict__ xb, ushort_t* __restrict__ Wt)
{
    const int tid = threadIdx.x;
    if (blockIdx.x < 300) {
        const int w = blockIdx.x / 100, rem = blockIdx.x % 100;
        const int k0 = (rem % 10) * 64, n0 = (rem / 10) * 64;
        const float* W = (w == 0) ? Wq : (w == 1) ? Wk : Wv;
        ushort_t* Wo = Wt + (size_t)w * D_DIM * D_DIM;

        __shared__ alignas(16) ushort_t st[64][72];
        const int r = tid >> 2, cs = (tid & 3) * 16;
        #pragma unroll
        for (int j = 0; j < 4; ++j) {
            float4 v = *reinterpret_cast<const float4*>(
                &W[(size_t)(k0 + r) * D_DIM + n0 + cs + j * 4]);
            st[r][cs + j * 4 + 0] = f32_to_bf16(v.x);
            st[r][cs + j * 4 + 1] = f32_to_bf16(v.y);
            st[r][cs + j * 4 + 2] = f32_to_bf16(v.z);
            st[r][cs + j * 4 + 3] = f32_to_bf16(v.w);
        }
        __syncthreads();
        const int nr = tid >> 2, ks = (tid & 3) * 16;
        ushort_t tmp[16];
        #pragma unroll
        for (int j = 0; j < 16; ++j) tmp[j] = st[ks + j][nr];
        ushort_t* dst = &Wo[(size_t)(n0 + nr) * D_DIM + k0 + ks];
        *reinterpret_cast<short8*>(dst)     = *reinterpret_cast<const short8*>(&tmp[0]);
        *reinterpret_cast<short8*>(dst + 8) = *reinterpret_cast<const short8*>(&tmp[8]);
    } else {
        const int n8 = (B_DIM * T_DIM * D_DIM) / 8;
        for (int i = (blockIdx.x - 300) * 256 + tid; i < n8; i += 2048 * 256) {
            float4 a = *reinterpret_cast<const float4*>(&x[i * 8]);
            float4 b = *reinterpret_cast<const float4*>(&x[i * 8 + 4]);
            ushort_t o[8] = {f32_to_bf16(a.x), f32_to_bf16(a.y), f32_to_bf16(a.z), f32_to_bf16(a.w),
                             f32_to_bf16(b.x), f32_to_bf16(b.y), f32_to_bf16(b.z), f32_to_bf16(b.w)};
            *reinterpret_cast<short8*>(&xb[i * 8]) = *reinterpret_cast<const short8*>(o);
        }
    }
}

// ---------------------------------------------------------------------------
// Kernel B: bf16 MFMA GEMM. Outputs written in 32x32x16-MFMA FRAGMENT layouts:
//  QF: (((hb*32+s)*4+kc)*64 + lane)*8+jj  = Q[32s+(l&31)][64h+16kc+8(l>>5)+jj]
//  KF: ((((hb*16+kt)*2+f)*4+kc)*64+lane)*8+jj = K[64kt+32f+(l&31)][...d...]
//  VF: ((((hb*16+kt)*4+c)*2+df)*64+lane)*8+jj = V[64kt+16c+8(l>>5)+jj][64h+32df+(l&31)]
// Also computes qs = sign(sum|Q_h|)*mask and km16 = sign(sum|K_h|) in-epilogue.
// ---------------------------------------------------------------------------
__global__ __launch_bounds__(256) void gemm_qkv(
    const ushort_t* __restrict__ xb, const ushort_t* __restrict__ Wt,
    const int* __restrict__ msk,
    ushort_t* __restrict__ QF, ushort_t* __restrict__ KF, ushort_t* __restrict__ VF,
    float* __restrict__ qs, ushort_t* __restrict__ km16)
{
    const int L = blockIdx.x;
    const int xcd = L & 7, j = L >> 3;
    const int m0 = (xcd * 8 + (j & 7)) * 128;
    const int nz = j >> 3;               // 0..14
    const int n0 = (nz % 5) * 128;
    const int w  = nz / 5;

    const ushort_t* Wm = Wt + (size_t)w * D_DIM * D_DIM;

    __shared__ alignas(16) ushort_t As[128 * 64];
    __shared__ alignas(16) ushort_t Bs[128 * 64];

    const int tid = threadIdx.x;
    const int lane = tid & 63, wave = tid >> 6;
    const int lo = lane & 15, g = lane >> 4;
    const int wm = wave >> 1, wn = wave & 1;
    const int srow = tid >> 3, schunk = tid & 7;

    f32x4 acc[4][4];
    #pragma unroll
    for (int i = 0; i < 4; ++i)
        #pragma unroll
        for (int jj = 0; jj < 4; ++jj) acc[i][jj] = (f32x4){0.f, 0.f, 0.f, 0.f};

    for (int k0 = 0; k0 < D_DIM; k0 += 64) {
        #pragma unroll
        for (int i = 0; i < 4; ++i) {
            int row = i * 32 + srow;
            int sc = schunk ^ (row & 7);
            gload16(&xb[(size_t)(m0 + row) * D_DIM + k0 + sc * 8], &As[i * 2048 + tid * 8]);
            gload16(&Wm[(size_t)(n0 + row) * D_DIM + k0 + sc * 8], &Bs[i * 2048 + tid * 8]);
        }
        __syncthreads();
        #pragma unroll
        for (int ks = 0; ks < 2; ++ks) {
            short8 af[4], bf[4];
            #pragma unroll
            for (int t = 0; t < 4; ++t) {
                int arow = wm * 64 + t * 16 + lo;
                int ach = (ks * 4 + g) ^ (arow & 7);
                af[t] = *reinterpret_cast<const short8*>(&As[arow * 64 + ach * 8]);
                int brow = wn * 64 + t * 16 + lo;
                int bch = (ks * 4 + g) ^ (brow & 7);
                bf[t] = *reinterpret_cast<const short8*>(&Bs[brow * 64 + bch * 8]);
            }
            __builtin_amdgcn_s_setprio(1);
            #pragma unroll
            for (int mi = 0; mi < 4; ++mi)
                #pragma unroll
                for (int ni = 0; ni < 4; ++ni)
                    acc[mi][ni] = __builtin_amdgcn_mfma_f32_16x16x32_bf16(
                        af[mi], bf[ni], acc[mi][ni], 0, 0, 0);
            __builtin_amdgcn_s_setprio(0);
        }
        __syncthreads();
    }

    const int hh = (n0 >> 6) + wn;           // head 0..9 for this wave's half
    const int bb = m0 >> 10;                 // batch
    const int hb = hh * 8 + bb;
    const int ktw = ((m0 & 1023) >> 6) + wm; // 64-row tile index

    if (w == 2) {
        // V -> VF fragment layout; 4 consecutive keys pack into ushort4
        const int hiv = g >> 1, jj0 = (g & 1) * 4;
        #pragma unroll
        for (int mi = 0; mi < 4; ++mi)
            #pragma unroll
            for (int ni = 0; ni < 4; ++ni) {
                const int df = ni >> 1, l31v = (ni & 1) * 16 + lo;
                size_t idx = ((((size_t)(hb * 16 + ktw) * 4 + mi) * 2 + df) * 64
                              + hiv * 32 + l31v) * 8 + jj0;
                ushort4 o = make_ushort4(f32_to_bf16(acc[mi][ni][0]), f32_to_bf16(acc[mi][ni][1]),
                                         f32_to_bf16(acc[mi][ni][2]), f32_to_bf16(acc[mi][ni][3]));
                *reinterpret_cast<ushort4*>(&VF[idx]) = o;
            }
    } else {
        // sign masks (reduce |acc| over the head's 64 cols: 4 ni x 16 lanes)
        #pragma unroll
        for (int mi = 0; mi < 4; ++mi)
            #pragma unroll
            for (int r = 0; r < 4; ++r) {
                float s_ = fabsf(acc[mi][0][r]) + fabsf(acc[mi][1][r])
                         + fabsf(acc[mi][2][r]) + fabsf(acc[mi][3][r]);
                #pragma unroll
                for (int m = 1; m < 16; m <<= 1) s_ += __shfl_xor(s_, m);
                if (lo == 0) {
                    int row = m0 + wm * 64 + mi * 16 + g * 4 + r;
                    int rowid = hh * 8192 + row;
                    if (w == 0) qs[rowid] = (s_ > 0.f ? 1.f : 0.f) * (float)msk[row];
                    else        km16[rowid] = (s_ > 0.f) ? (ushort_t)0x3F80 : (ushort_t)0;
                }
            }
        // fragment-layout stores
        const int hi2 = lo >> 3, jjq = lo & 7;
        const int s32base = ((m0 & 1023) + wm * 64) >> 5;
        #pragma unroll
        for (int mi = 0; mi < 4; ++mi)
            #pragma unroll
            for (int ni = 0; ni < 4; ++ni)
                #pragma unroll
                for (int r = 0; r < 4; ++r) {
                    int l31 = (mi & 1) * 16 + g * 4 + r;
                    if (w == 0) {
                        int s32 = s32base + (mi >> 1);
                        size_t idx = (((size_t)(hb * 32 + s32) * 4 + ni) * 64
                                      + hi2 * 32 + l31) * 8 + jjq;
                        QF[idx] = f32_to_bf16(acc[mi][ni][r]);
                    } else {
                        int f = (mi >> 1) & 1;
                        size_t idx = ((((size_t)(hb * 16 + ktw) * 2 + f) * 4 + ni) * 64
                                      + hi2 * 32 + l31) * 8 + jjq;
                        KF[idx] = f32_to_bf16(acc[mi][ni][r]);
                    }
                }
    }
}

// ---------------------------------------------------------------------------
// Kernel C: wave-independent flash attention, 32x32x16 MFMA, swapped QK^T.
// One WAVE = one (b,h, 32-row q-strip). Zero barriers; coalesced fragment
// loads; P stays in registers (cvt_pk_bf16 + v_permlane32_swap).
// NEW: K-operand software double-buffer (2-deep, static kA/kB regs) — K[kt+1]
// loads issue before tile kt's compute, hiding L2 latency under softmax+PV.
// ---------------------------------------------------------------------------
#define LOADK(KB_, KT_IDX) do {                                                  \
    const ushort_t* KT_ = &KFh[(KT_IDX) * 4096];                                 \
    _Pragma("unroll")                                                            \
    for (int f_ = 0; f_ < 2; ++f_)                                               \
        _Pragma("unroll")                                                        \
        for (int kc_ = 0; kc_ < 4; ++kc_)                                        \
            KB_[f_][kc_] = *reinterpret_cast<const short8*>(                     \
                &KT_[(f_ * 4 + kc_) * 512 + lane * 8]);                          \
} while (0)

#define COMPUTE_TILE(KBUF, KT_IDX) do {                                          \
    const int k0_ = (KT_IDX) * 64;                                               \
    const ushort_t* VT_ = &VFh[(size_t)(KT_IDX) * 4096];                         \
    short8 vfA_[2][2], vfB_[2][2];                                               \
    _Pragma("unroll")                                                            \
    for (int c_ = 0; c_ < 2; ++c_)                                               \
        _Pragma("unroll")                                                        \
        for (int df_ = 0; df_ < 2; ++df_)                                        \
            vfA_[c_][df_] = *reinterpret_cast<const short8*>(                    \
                &VT_[(c_ * 2 + df_) * 512 + lane * 8]);                          \
    ushort4 kq_[2][4];                                                           \
    _Pragma("unroll")                                                            \
    for (int f_ = 0; f_ < 2; ++f_)                                               \
        _Pragma("unroll")                                                        \
        for (int rr_ = 0; rr_ < 4; ++rr_)                                        \
            kq_[f_][rr_] = *reinterpret_cast<const ushort4*>(                    \
                &kmr[k0_ + f_ * 32 + rr_ * 8 + hi * 4]);                         \
    unsigned pk_[2][8];                                                          \
    _Pragma("unroll")                                                            \
    for (int f_ = 0; f_ < 2; ++f_) {                                             \
        f32x16 sf_;                                                              \
        _Pragma("unroll")                                                        \
        for (int i_ = 0; i_ < 16; ++i_) sf_[i_] = 0.f;                           \
        __builtin_amdgcn_s_setprio(1);                                           \
        _Pragma("unroll")                                                        \
        for (int kc_ = 0; kc_ < 4; ++kc_)                                        \
            sf_ = __builtin_amdgcn_mfma_f32_32x32x16_bf16(KBUF[f_][kc_],         \
                                                          qf[kc_], sf_, 0, 0, 0);\
        __builtin_amdgcn_s_setprio(0);                                           \
        if (f_ == 0) {                                                           \
            _Pragma("unroll")                                                    \
            for (int c_ = 0; c_ < 2; ++c_)                                       \
                _Pragma("unroll")                                                \
                for (int df_ = 0; df_ < 2; ++df_)                                \
                    vfB_[c_][df_] = *reinterpret_cast<const short8*>(            \
                        &VT_[((c_ + 2) * 2 + df_) * 512 + lane * 8]);            \
        }                                                                        \
        _Pragma("unroll")                                                        \
        for (int rr_ = 0; rr_ < 4; ++rr_) {                                      \
            const int kbase_ = k0_ + f_ * 32 + rr_ * 8 + hi * 4;                 \
            const ushort_t* kmv_ =                                               \
                reinterpret_cast<const ushort_t*>(&kq_[f_][rr_]);                \
            float p_[4];                                                         \
            _Pragma("unroll")                                                    \
            for (int ri_ = 0; ri_ < 4; ++ri_) {                                  \
                float cc_ = (kbase_ + ri_ >= trow) ? cB : cA;                    \
                cc_ = kmv_[ri_] ? cc_ : -1e30f;                                  \
                p_[ri_] = v_exp2(fmaf(sf_[rr_ * 4 + ri_], S2, cc_));             \
                lacc += p_[ri_];                                                 \
            }                                                                    \
            pk_[f_][rr_ * 2 + 0] = cvt_pk_bf16(p_[0], p_[1]);                    \
            pk_[f_][rr_ * 2 + 1] = cvt_pk_bf16(p_[2], p_[3]);                    \
        }                                                                        \
    }                                                                            \
    _Pragma("unroll")                                                            \
    for (int c_ = 0; c_ < 4; ++c_) {                                             \
        const int f_ = c_ >> 1, o_ = (c_ & 1) * 4;                               \
        unsigned a0_ = pk_[f_][o_ + 0], b0_ = pk_[f_][o_ + 2];                   \
        unsigned a1_ = pk_[f_][o_ + 1], b1_ = pk_[f_][o_ + 3];                   \
        if (v1) {                                                                \
            asm volatile("v_permlane32_swap_b32 %0, %1" : "+v"(b0_), "+v"(a0_)); \
            asm volatile("v_permlane32_swap_b32 %0, %1" : "+v"(b1_), "+v"(a1_)); \
        } else {                                                                 \
            asm volatile("v_permlane32_swap_b32 %0, %1" : "+v"(a0_), "+v"(b0_)); \
            asm volatile("v_permlane32_swap_b32 %0, %1" : "+v"(a1_), "+v"(b1_)); \
        }                                                                        \
        u32x4 pau_ = {a0_, a1_, b0_, b1_};                                       \
        short8 pa_ = __builtin_bit_cast(short8, pau_);                           \
        short8 v0_ = (c_ < 2) ? vfA_[c_][0] : vfB_[c_ - 2][0];                   \
        short8 v1f_ = (c_ < 2) ? vfA_[c_][1] : vfB_[c_ - 2][1];                  \
        __builtin_amdgcn_s_setprio(1);                                           \
        of0 = __builtin_amdgcn_mfma_f32_32x32x16_bf16(pa_, v0_, of0, 0, 0, 0);   \
        of1 = __builtin_amdgcn_mfma_f32_32x32x16_bf16(pa_, v1f_, of1, 0, 0, 0);  \
        __builtin_amdgcn_s_setprio(0);                                           \
    }                                                                            \
} while (0)

__global__ __launch_bounds__(256, 2) void attn_wave(
    const ushort_t* __restrict__ QF, const ushort_t* __restrict__ KF,
    const ushort_t* __restrict__ VF, const float* __restrict__ qs,
    const ushort_t* __restrict__ km16, float* __restrict__ out)
{
    __shared__ float scs[4][32];
    const int tid = threadIdx.x, lane = tid & 63, wave = tid >> 6;
    const int l31 = lane & 31, hi = lane >> 5;

    const int bid = blockIdx.x, xcd = bid & 7, j = bid >> 3;
    const int g8 = xcd + 8 * (j % 10), qg = j / 10;
    const int s = SPERM[qg * 4 + wave], q0 = s * 32;
    const int b = g8 & 7, h = g8 >> 3, hb = h * 8 + b;

    // --- probe permlane32_swap direction (HW variant), wave-uniform ---
    unsigned pva = (unsigned)lane, pvb = 64u + (unsigned)lane;
    asm volatile("v_permlane32_swap_b32 %0, %1" : "+v"(pva), "+v"(pvb));
    const bool v1 = (__builtin_amdgcn_readfirstlane((int)pva) >= 96);

    const ushort_t* QFh = QF + (size_t)(hb * 32 + s) * 2048;
    const ushort_t* KFh = KF + (size_t)hb * 16 * 4096;
    const ushort_t* VFh = VF + (size_t)hb * 16 * 4096;
    const ushort_t* kmr = km16 + (size_t)hb * 1024;

    // Q fragments (B-operand), loop-invariant
    short8 qf[4];
    #pragma unroll
    for (int kc = 0; kc < 4; ++kc)
        qf[kc] = *reinterpret_cast<const short8*>(&QFh[kc * 512 + lane * 8]);

    // per-row shift M: any unpadded key strictly before row q0+l31?
    bool anyPrior = false;
    for (int c = 0; c < (q0 >> 6); ++c) {
        ushort_t v = kmr[c * 64 + lane];
        anyPrior = anyPrior || (__ballot(v != 0) != 0ull);
    }
    float M;
    {
        ushort_t v = kmr[(q0 & ~63) + lane];
        unsigned long long bal = __ballot(v != 0);
        unsigned long long pre = bal & ((1ull << ((q0 & 63) + l31)) - 1ull);
        M = (anyPrior || pre != 0ull) ? 16.f : -9984.f;
    }
    const float cA = -M * LOG2E;
    const float cB = cA - 10000.0f * LOG2E;
    const float S2 = 0.125f * LOG2E;
    const int trow = q0 + l31;

    float lacc = 0.f;
    f32x16 of0, of1;
    #pragma unroll
    for (int i = 0; i < 16; ++i) { of0[i] = 0.f; of1[i] = 0.f; }

    const int ktend = (s == 0) ? 16 : ((s >> 1) + 1);

    // ---- 2-deep K-prefetch pipeline (static kA/kB buffers) ----
    short8 kA[2][4], kB[2][4];
    LOADK(kA, 0);
    int kt = 0;
    for (; kt + 2 <= ktend; kt += 2) {
        LOADK(kB, kt + 1);
        COMPUTE_TILE(kA, kt);
        if (kt + 2 < ktend) LOADK(kA, kt + 2);
        COMPUTE_TILE(kB, kt + 1);
    }
    if (kt < ktend) COMPUTE_TILE(kA, kt);

    // epilogue: row scale qs/l distributed via tiny per-wave LDS slice
    float ltot = lacc + __shfl_xor(lacc, 32);
    if (hi == 0)
        scs[wave][l31] = qs[(size_t)hb * 1024 + q0 + l31] / ltot;
    const size_t obase = ((size_t)b * T_DIM + q0) * D_DIM + h * 64;
    #pragma unroll
    for (int reg = 0; reg < 16; ++reg) {
        const int qrow = (reg & 3) + 8 * (reg >> 2) + 4 * hi;
        const float sc = scs[wave][qrow];
        out[obase + (size_t)qrow * D_DIM + l31]      = of0[reg] * sc;
        out[obase + (size_t)qrow * D_DIM + 32 + l31] = of1[reg] * sc;
    }
}

// ---------------------------------------------------------------------------
extern "C" void kernel_launch(void* const* d_in, const int* in_sizes, int n_in,
                              void* d_out, int out_size, void* d_ws, size_t ws_size,
                              hipStream_t stream)
{
    const float* x   = (const float*)d_in[0];
    const int*   msk = (const int*)d_in[1];
    const float* Wq  = (const float*)d_in[2];
    const float* Wk  = (const float*)d_in[3];
    const float* Wv  = (const float*)d_in[4];
    float* out = (float*)d_out;

    // workspace layout (bytes)
    char* ws = (char*)d_ws;
    ushort_t* xb = (ushort_t*)(ws);                    // 10,485,760
    ushort_t* Wt = (ushort_t*)(ws + 10485760);         //  2,457,600
    ushort_t* QF = (ushort_t*)(ws + 12943360);         // 10,485,760
    ushort_t* KF = (ushort_t*)(ws + 23429120);         // 10,485,760
    ushort_t* VF = (ushort_t*)(ws + 33914880);         // 10,485,760
    float*    qs = (float*)(ws + 44400640);            //    327,680
    ushort_t* km = (ushort_t*)(ws + 44728320);         //    163,840
    if (ws_size < 44892160) return;

    convwt<<<2348, 256, 0, stream>>>(x, Wq, Wk, Wv, xb, Wt);
    gemm_qkv<<<960, 256, 0, stream>>>(xb, Wt, msk, QF, KF, VF, qs, km);
    attn_wave<<<640, 256, 0, stream>>>(QF, KF, VF, qs, km, out);
}

// Round 10
// 79.180 us; speedup vs baseline: 1.0084x; 1.0084x over previous
//
#include <hip/hip_runtime.h>
#include <hip/hip_bf16.h>
#include <stdint.h>

// B=8, T=1024, D=U=640, H=10, d=64
#define B_DIM 8
#define T_DIM 1024
#define D_DIM 640
#define H_DIM 10
#define LOG2E 1.442695041f

typedef unsigned short ushort_t;
typedef __attribute__((ext_vector_type(8))) short short8;
typedef __attribute__((ext_vector_type(4))) float f32x4;
typedef __attribute__((ext_vector_type(16))) float f32x16;
typedef __attribute__((ext_vector_type(4))) unsigned int u32x4;

__device__ __forceinline__ ushort_t f32_to_bf16(float f) {
    unsigned int u = __builtin_bit_cast(unsigned int, f);
    u += 0x7fffu + ((u >> 16) & 1u);   // RNE
    return (ushort_t)(u >> 16);
}
__device__ __forceinline__ float v_exp2(float x) {
    float r; asm("v_exp_f32 %0, %1" : "=v"(r) : "v"(x)); return r;
}
__device__ __forceinline__ unsigned cvt_pk_bf16(float a, float b) {
    unsigned r; asm("v_cvt_pk_bf16_f32 %0, %1, %2" : "=v"(r) : "v"(a), "v"(b)); return r;
}
// async global->LDS (GEMM staging only)
__device__ __forceinline__ void gload16(const void* g, void* l) {
    auto gp = reinterpret_cast<const __attribute__((address_space(1))) uint32_t*>(
        reinterpret_cast<uintptr_t>(g));
    auto lp = reinterpret_cast<__attribute__((address_space(3))) uint32_t*>(
        reinterpret_cast<uintptr_t>(l));
    __builtin_amdgcn_global_load_lds(gp, lp, 16, 0, 0);
}

// strips sorted heavy-first by tile count: 0(16),31(16),30(16),29(15),...
__constant__ int SPERM[32] = {0,31,30,29,28,27,26,25,24,23,22,21,20,19,18,17,
                              16,15,14,13,12,11,10,9,8,7,6,5,4,3,2,1};

// ---------------------------------------------------------------------------
// Kernel A: fused { W transpose->bf16 (blocks 0..299) , x->bf16 (blocks 300+) }
// ---------------------------------------------------------------------------
__global__ __launch_bounds__(256) void convwt(
    const float* __restrict__ x,
    const float* __restrict__ Wq, const float* __restrict__ Wk, const float* __restrict__ Wv,
    ushort_t* __restrict__ xb, ushort_t* __restrict__ Wt)
{
    const int tid = threadIdx.x;
    if (blockIdx.x < 300) {
        const int w = blockIdx.x / 100, rem = blockIdx.x % 100;
        const int k0 = (rem % 10) * 64, n0 = (rem / 10) * 64;
        const float* W = (w == 0) ? Wq : (w == 1) ? Wk : Wv;
        ushort_t* Wo = Wt + (size_t)w * D_DIM * D_DIM;

        __shared__ alignas(16) ushort_t st[64][72];
        const int r = tid >> 2, cs = (tid & 3) * 16;
        #pragma unroll
        for (int j = 0; j < 4; ++j) {
            float4 v = *reinterpret_cast<const float4*>(
                &W[(size_t)(k0 + r) * D_DIM + n0 + cs + j * 4]);
            st[r][cs + j * 4 + 0] = f32_to_bf16(v.x);
            st[r][cs + j * 4 + 1] = f32_to_bf16(v.y);
            st[r][cs + j * 4 + 2] = f32_to_bf16(v.z);
            st[r][cs + j * 4 + 3] = f32_to_bf16(v.w);
        }
        __syncthreads();
        const int nr = tid >> 2, ks = (tid & 3) * 16;
        ushort_t tmp[16];
        #pragma unroll
        for (int j = 0; j < 16; ++j) tmp[j] = st[ks + j][nr];
        ushort_t* dst = &Wo[(size_t)(n0 + nr) * D_DIM + k0 + ks];
        *reinterpret_cast<short8*>(dst)     = *reinterpret_cast<const short8*>(&tmp[0]);
        *reinterpret_cast<short8*>(dst + 8) = *reinterpret_cast<const short8*>(&tmp[8]);
    } else {
        const int n8 = (B_DIM * T_DIM * D_DIM) / 8;
        for (int i = (blockIdx.x - 300) * 256 + tid; i < n8; i += 2048 * 256) {
            float4 a = *reinterpret_cast<const float4*>(&x[i * 8]);
            float4 b = *reinterpret_cast<const float4*>(&x[i * 8 + 4]);
            ushort_t o[8] = {f32_to_bf16(a.x), f32_to_bf16(a.y), f32_to_bf16(a.z), f32_to_bf16(a.w),
                             f32_to_bf16(b.x), f32_to_bf16(b.y), f32_to_bf16(b.z), f32_to_bf16(b.w)};
            *reinterpret_cast<short8*>(&xb[i * 8]) = *reinterpret_cast<const short8*>(o);
        }
    }
}

// ---------------------------------------------------------------------------
// Kernel B: bf16 MFMA GEMM. Outputs written in 32x32x16-MFMA FRAGMENT layouts:
//  QF: (((hb*32+s)*4+kc)*64 + lane)*8+jj  = Q[32s+(l&31)][64h+16kc+8(l>>5)+jj]
//  KF: ((((hb*16+kt)*2+f)*4+kc)*64+lane)*8+jj = K[64kt+32f+(l&31)][...d...]
//  VF: ((((hb*16+kt)*4+c)*2+df)*64+lane)*8+jj = V[64kt+16c+8(l>>5)+jj][64h+32df+(l&31)]
// Also computes qs = sign(sum|Q_h|)*mask and km16 = sign(sum|K_h|) in-epilogue.
// ---------------------------------------------------------------------------
__global__ __launch_bounds__(256) void gemm_qkv(
    const ushort_t* __restrict__ xb, const ushort_t* __restrict__ Wt,
    const int* __restrict__ msk,
    ushort_t* __restrict__ QF, ushort_t* __restrict__ KF, ushort_t* __restrict__ VF,
    float* __restrict__ qs, ushort_t* __restrict__ km16)
{
    const int L = blockIdx.x;
    const int xcd = L & 7, j = L >> 3;
    const int m0 = (xcd * 8 + (j & 7)) * 128;
    const int nz = j >> 3;               // 0..14
    const int n0 = (nz % 5) * 128;
    const int w  = nz / 5;

    const ushort_t* Wm = Wt + (size_t)w * D_DIM * D_DIM;

    __shared__ alignas(16) ushort_t As[128 * 64];
    __shared__ alignas(16) ushort_t Bs[128 * 64];

    const int tid = threadIdx.x;
    const int lane = tid & 63, wave = tid >> 6;
    const int lo = lane & 15, g = lane >> 4;
    const int wm = wave >> 1, wn = wave & 1;
    const int srow = tid >> 3, schunk = tid & 7;

    f32x4 acc[4][4];
    #pragma unroll
    for (int i = 0; i < 4; ++i)
        #pragma unroll
        for (int jj = 0; jj < 4; ++jj) acc[i][jj] = (f32x4){0.f, 0.f, 0.f, 0.f};

    for (int k0 = 0; k0 < D_DIM; k0 += 64) {
        #pragma unroll
        for (int i = 0; i < 4; ++i) {
            int row = i * 32 + srow;
            int sc = schunk ^ (row & 7);
            gload16(&xb[(size_t)(m0 + row) * D_DIM + k0 + sc * 8], &As[i * 2048 + tid * 8]);
            gload16(&Wm[(size_t)(n0 + row) * D_DIM + k0 + sc * 8], &Bs[i * 2048 + tid * 8]);
        }
        __syncthreads();
        #pragma unroll
        for (int ks = 0; ks < 2; ++ks) {
            short8 af[4], bf[4];
            #pragma unroll
            for (int t = 0; t < 4; ++t) {
                int arow = wm * 64 + t * 16 + lo;
                int ach = (ks * 4 + g) ^ (arow & 7);
                af[t] = *reinterpret_cast<const short8*>(&As[arow * 64 + ach * 8]);
                int brow = wn * 64 + t * 16 + lo;
                int bch = (ks * 4 + g) ^ (brow & 7);
                bf[t] = *reinterpret_cast<const short8*>(&Bs[brow * 64 + bch * 8]);
            }
            __builtin_amdgcn_s_setprio(1);
            #pragma unroll
            for (int mi = 0; mi < 4; ++mi)
                #pragma unroll
                for (int ni = 0; ni < 4; ++ni)
                    acc[mi][ni] = __builtin_amdgcn_mfma_f32_16x16x32_bf16(
                        af[mi], bf[ni], acc[mi][ni], 0, 0, 0);
            __builtin_amdgcn_s_setprio(0);
        }
        __syncthreads();
    }

    const int hh = (n0 >> 6) + wn;           // head 0..9 for this wave's half
    const int bb = m0 >> 10;                 // batch
    const int hb = hh * 8 + bb;
    const int ktw = ((m0 & 1023) >> 6) + wm; // 64-row tile index

    if (w == 2) {
        // V -> VF fragment layout; 4 consecutive keys pack into ushort4
        const int hiv = g >> 1, jj0 = (g & 1) * 4;
        #pragma unroll
        for (int mi = 0; mi < 4; ++mi)
            #pragma unroll
            for (int ni = 0; ni < 4; ++ni) {
                const int df = ni >> 1, l31v = (ni & 1) * 16 + lo;
                size_t idx = ((((size_t)(hb * 16 + ktw) * 4 + mi) * 2 + df) * 64
                              + hiv * 32 + l31v) * 8 + jj0;
                ushort4 o = make_ushort4(f32_to_bf16(acc[mi][ni][0]), f32_to_bf16(acc[mi][ni][1]),
                                         f32_to_bf16(acc[mi][ni][2]), f32_to_bf16(acc[mi][ni][3]));
                *reinterpret_cast<ushort4*>(&VF[idx]) = o;
            }
    } else {
        // sign masks (reduce |acc| over the head's 64 cols: 4 ni x 16 lanes)
        #pragma unroll
        for (int mi = 0; mi < 4; ++mi)
            #pragma unroll
            for (int r = 0; r < 4; ++r) {
                float s_ = fabsf(acc[mi][0][r]) + fabsf(acc[mi][1][r])
                         + fabsf(acc[mi][2][r]) + fabsf(acc[mi][3][r]);
                #pragma unroll
                for (int m = 1; m < 16; m <<= 1) s_ += __shfl_xor(s_, m);
                if (lo == 0) {
                    int row = m0 + wm * 64 + mi * 16 + g * 4 + r;
                    int rowid = hh * 8192 + row;
                    if (w == 0) qs[rowid] = (s_ > 0.f ? 1.f : 0.f) * (float)msk[row];
                    else        km16[rowid] = (s_ > 0.f) ? (ushort_t)0x3F80 : (ushort_t)0;
                }
            }
        // fragment-layout stores
        const int hi2 = lo >> 3, jjq = lo & 7;
        const int s32base = ((m0 & 1023) + wm * 64) >> 5;
        #pragma unroll
        for (int mi = 0; mi < 4; ++mi)
            #pragma unroll
            for (int ni = 0; ni < 4; ++ni)
                #pragma unroll
                for (int r = 0; r < 4; ++r) {
                    int l31 = (mi & 1) * 16 + g * 4 + r;
                    if (w == 0) {
                        int s32 = s32base + (mi >> 1);
                        size_t idx = (((size_t)(hb * 32 + s32) * 4 + ni) * 64
                                      + hi2 * 32 + l31) * 8 + jjq;
                        QF[idx] = f32_to_bf16(acc[mi][ni][r]);
                    } else {
                        int f = (mi >> 1) & 1;
                        size_t idx = ((((size_t)(hb * 16 + ktw) * 2 + f) * 4 + ni) * 64
                                      + hi2 * 32 + l31) * 8 + jjq;
                        KF[idx] = f32_to_bf16(acc[mi][ni][r]);
                    }
                }
    }
}

// ---------------------------------------------------------------------------
// Kernel C: flash attention with 4-way k-split per strip.
// Block = (b,h, strip of 32 q-rows); wave w handles tiles kt = w, w+4, ...
// Fixed-shift softmax -> partial (O,l) exactly addable; LDS merge + wave-0
// epilogue. No atomics, one __syncthreads per block.
// ---------------------------------------------------------------------------
#define DO_TILE(KT_IDX) do {                                                     \
    const int k0_ = (KT_IDX) * 64;                                               \
    const ushort_t* KT_ = &KFh[(size_t)(KT_IDX) * 4096];                         \
    const ushort_t* VT_ = &VFh[(size_t)(KT_IDX) * 4096];                         \
    short8 kA_[2][4];                                                            \
    _Pragma("unroll")                                                            \
    for (int f_ = 0; f_ < 2; ++f_)                                               \
        _Pragma("unroll")                                                        \
        for (int kc_ = 0; kc_ < 4; ++kc_)                                        \
            kA_[f_][kc_] = *reinterpret_cast<const short8*>(                     \
                &KT_[(f_ * 4 + kc_) * 512 + lane * 8]);                          \
    short8 vfA_[2][2], vfB_[2][2];                                               \
    _Pragma("unroll")                                                            \
    for (int c_ = 0; c_ < 2; ++c_)                                               \
        _Pragma("unroll")                                                        \
        for (int df_ = 0; df_ < 2; ++df_)                                        \
            vfA_[c_][df_] = *reinterpret_cast<const short8*>(                    \
                &VT_[(c_ * 2 + df_) * 512 + lane * 8]);                          \
    ushort4 kq_[2][4];                                                           \
    _Pragma("unroll")                                                            \
    for (int f_ = 0; f_ < 2; ++f_)                                               \
        _Pragma("unroll")                                                        \
        for (int rr_ = 0; rr_ < 4; ++rr_)                                        \
            kq_[f_][rr_] = *reinterpret_cast<const ushort4*>(                    \
                &kmr[k0_ + f_ * 32 + rr_ * 8 + hi * 4]);                         \
    unsigned pk_[2][8];                                                          \
    _Pragma("unroll")                                                            \
    for (int f_ = 0; f_ < 2; ++f_) {                                             \
        f32x16 sf_;                                                              \
        _Pragma("unroll")                                                        \
        for (int i_ = 0; i_ < 16; ++i_) sf_[i_] = 0.f;                           \
        __builtin_amdgcn_s_setprio(1);                                           \
        _Pragma("unroll")                                                        \
        for (int kc_ = 0; kc_ < 4; ++kc_)                                        \
            sf_ = __builtin_amdgcn_mfma_f32_32x32x16_bf16(kA_[f_][kc_],          \
                                                          qf[kc_], sf_, 0, 0, 0);\
        __builtin_amdgcn_s_setprio(0);                                           \
        if (f_ == 0) {                                                           \
            _Pragma("unroll")                                                    \
            for (int c_ = 0; c_ < 2; ++c_)                                       \
                _Pragma("unroll")                                                \
                for (int df_ = 0; df_ < 2; ++df_)                                \
                    vfB_[c_][df_] = *reinterpret_cast<const short8*>(            \
                        &VT_[((c_ + 2) * 2 + df_) * 512 + lane * 8]);            \
        }                                                                        \
        _Pragma("unroll")                                                        \
        for (int rr_ = 0; rr_ < 4; ++rr_) {                                      \
            const int kbase_ = k0_ + f_ * 32 + rr_ * 8 + hi * 4;                 \
            const ushort_t* kmv_ =                                               \
                reinterpret_cast<const ushort_t*>(&kq_[f_][rr_]);                \
            float p_[4];                                                         \
            _Pragma("unroll")                                                    \
            for (int ri_ = 0; ri_ < 4; ++ri_) {                                  \
                float cc_ = (kbase_ + ri_ >= trow) ? cB : cA;                    \
                cc_ = kmv_[ri_] ? cc_ : -1e30f;                                  \
                p_[ri_] = v_exp2(fmaf(sf_[rr_ * 4 + ri_], S2, cc_));             \
                lacc += p_[ri_];                                                 \
            }                                                                    \
            pk_[f_][rr_ * 2 + 0] = cvt_pk_bf16(p_[0], p_[1]);                    \
            pk_[f_][rr_ * 2 + 1] = cvt_pk_bf16(p_[2], p_[3]);                    \
        }                                                                        \
    }                                                                            \
    _Pragma("unroll")                                                            \
    for (int c_ = 0; c_ < 4; ++c_) {                                             \
        const int f_ = c_ >> 1, o_ = (c_ & 1) * 4;                               \
        unsigned a0_ = pk_[f_][o_ + 0], b0_ = pk_[f_][o_ + 2];                   \
        unsigned a1_ = pk_[f_][o_ + 1], b1_ = pk_[f_][o_ + 3];                   \
        if (v1) {                                                                \
            asm volatile("v_permlane32_swap_b32 %0, %1" : "+v"(b0_), "+v"(a0_)); \
            asm volatile("v_permlane32_swap_b32 %0, %1" : "+v"(b1_), "+v"(a1_)); \
        } else {                                                                 \
            asm volatile("v_permlane32_swap_b32 %0, %1" : "+v"(a0_), "+v"(b0_)); \
            asm volatile("v_permlane32_swap_b32 %0, %1" : "+v"(a1_), "+v"(b1_)); \
        }                                                                        \
        u32x4 pau_ = {a0_, a1_, b0_, b1_};                                       \
        short8 pa_ = __builtin_bit_cast(short8, pau_);                           \
        short8 v0_ = (c_ < 2) ? vfA_[c_][0] : vfB_[c_ - 2][0];                   \
        short8 v1f_ = (c_ < 2) ? vfA_[c_][1] : vfB_[c_ - 2][1];                  \
        __builtin_amdgcn_s_setprio(1);                                           \
        of0 = __builtin_amdgcn_mfma_f32_32x32x16_bf16(pa_, v0_, of0, 0, 0, 0);   \
        of1 = __builtin_amdgcn_mfma_f32_32x32x16_bf16(pa_, v1f_, of1, 0, 0, 0);  \
        __builtin_amdgcn_s_setprio(0);                                           \
    }                                                                            \
} while (0)

__global__ __launch_bounds__(256, 3) void attn_strip(
    const ushort_t* __restrict__ QF, const ushort_t* __restrict__ KF,
    const ushort_t* __restrict__ VF, const float* __restrict__ qs,
    const ushort_t* __restrict__ km16, float* __restrict__ out)
{
    __shared__ alignas(16) float mrg[3 * 64 * 36];   // 27,648 B

    const int tid = threadIdx.x, lane = tid & 63, wave = tid >> 6;
    const int l31 = lane & 31, hi = lane >> 5;

    // mapping: block = (b,h, strip). same-(b,h) on one XCD; heavy strips first.
    const int bid = blockIdx.x;                 // 0..2559
    const int xcd = bid & 7, i = bid >> 3;      // i 0..319
    const int sr = i / 10, grp = i % 10;
    const int g8 = xcd + 8 * grp;               // (b,h) group 0..79
    const int s = SPERM[sr], q0 = s * 32;
    const int b = g8 & 7, h = g8 >> 3, hb = h * 8 + b;

    // --- probe permlane32_swap direction (HW variant), wave-uniform ---
    unsigned pva = (unsigned)lane, pvb = 64u + (unsigned)lane;
    asm volatile("v_permlane32_swap_b32 %0, %1" : "+v"(pva), "+v"(pvb));
    const bool v1 = (__builtin_amdgcn_readfirstlane((int)pva) >= 96);

    const ushort_t* QFh = QF + (size_t)(hb * 32 + s) * 2048;
    const ushort_t* KFh = KF + (size_t)hb * 16 * 4096;
    const ushort_t* VFh = VF + (size_t)hb * 16 * 4096;
    const ushort_t* kmr = km16 + (size_t)hb * 1024;

    // Q fragments (B-operand), loop-invariant; all 4 waves load same -> L1 hit
    short8 qf[4];
    #pragma unroll
    for (int kc = 0; kc < 4; ++kc)
        qf[kc] = *reinterpret_cast<const short8*>(&QFh[kc * 512 + lane * 8]);

    // per-row shift M: any unpadded key strictly before row q0+l31?
    bool anyPrior = false;
    for (int c = 0; c < (q0 >> 6); ++c) {
        ushort_t v = kmr[c * 64 + lane];
        anyPrior = anyPrior || (__ballot(v != 0) != 0ull);
    }
    float M;
    {
        ushort_t v = kmr[(q0 & ~63) + lane];
        unsigned long long bal = __ballot(v != 0);
        unsigned long long pre = bal & ((1ull << ((q0 & 63) + l31)) - 1ull);
        M = (anyPrior || pre != 0ull) ? 16.f : -9984.f;
    }
    const float cA = -M * LOG2E;
    const float cB = cA - 10000.0f * LOG2E;
    const float S2 = 0.125f * LOG2E;
    const int trow = q0 + l31;

    float lacc = 0.f;
    f32x16 of0, of1;
    #pragma unroll
    for (int i2 = 0; i2 < 16; ++i2) { of0[i2] = 0.f; of1[i2] = 0.f; }

    const int ktend = (s == 0) ? 16 : ((s >> 1) + 1);

    // wave's interleaved tile subset
    for (int kt = wave; kt < ktend; kt += 4)
        DO_TILE(kt);

    // ---- merge partials: waves 1..3 -> LDS, wave 0 sums ----
    if (wave != 0) {
        float* dst = &mrg[((wave - 1) * 64 + lane) * 36];
        #pragma unroll
        for (int q = 0; q < 4; ++q) {
            reinterpret_cast<float4*>(dst)[q] =
                make_float4(of0[q * 4 + 0], of0[q * 4 + 1], of0[q * 4 + 2], of0[q * 4 + 3]);
            reinterpret_cast<float4*>(dst)[4 + q] =
                make_float4(of1[q * 4 + 0], of1[q * 4 + 1], of1[q * 4 + 2], of1[q * 4 + 3]);
        }
        dst[32] = lacc;
    }
    __syncthreads();
    if (wave == 0) {
        #pragma unroll
        for (int w2 = 0; w2 < 3; ++w2) {
            const float* src = &mrg[(w2 * 64 + lane) * 36];
            #pragma unroll
            for (int q = 0; q < 4; ++q) {
                float4 t0 = reinterpret_cast<const float4*>(src)[q];
                of0[q * 4 + 0] += t0.x; of0[q * 4 + 1] += t0.y;
                of0[q * 4 + 2] += t0.z; of0[q * 4 + 3] += t0.w;
                float4 t1 = reinterpret_cast<const float4*>(src)[4 + q];
                of1[q * 4 + 0] += t1.x; of1[q * 4 + 1] += t1.y;
                of1[q * 4 + 2] += t1.z; of1[q * 4 + 3] += t1.w;
            }
            lacc += src[32];
        }
        float ltot = lacc + __shfl_xor(lacc, 32);
        float scale = qs[(size_t)hb * 1024 + q0 + l31] / ltot;   // lane l: row l31
        const size_t obase = ((size_t)b * T_DIM + q0) * D_DIM + h * 64;
        #pragma unroll
        for (int reg = 0; reg < 16; ++reg) {
            const int qrow = (reg & 3) + 8 * (reg >> 2) + 4 * hi;
            const float sc = __shfl(scale, qrow);
            out[obase + (size_t)qrow * D_DIM + l31]      = of0[reg] * sc;
            out[obase + (size_t)qrow * D_DIM + 32 + l31] = of1[reg] * sc;
        }
    }
}

// ---------------------------------------------------------------------------
extern "C" void kernel_launch(void* const* d_in, const int* in_sizes, int n_in,
                              void* d_out, int out_size, void* d_ws, size_t ws_size,
                              hipStream_t stream)
{
    const float* x   = (const float*)d_in[0];
    const int*   msk = (const int*)d_in[1];
    const float* Wq  = (const float*)d_in[2];
    const float* Wk  = (const float*)d_in[3];
    const float* Wv  = (const float*)d_in[4];
    float* out = (float*)d_out;

    // workspace layout (bytes)
    char* ws = (char*)d_ws;
    ushort_t* xb = (ushort_t*)(ws);                    // 10,485,760
    ushort_t* Wt = (ushort_t*)(ws + 10485760);         //  2,457,600
    ushort_t* QF = (ushort_t*)(ws + 12943360);         // 10,485,760
    ushort_t* KF = (ushort_t*)(ws + 23429120);         // 10,485,760
    ushort_t* VF = (ushort_t*)(ws + 33914880);         // 10,485,760
    float*    qs = (float*)(ws + 44400640);            //    327,680
    ushort_t* km = (ushort_t*)(ws + 44728320);         //    163,840
    if (ws_size < 44892160) return;

    convwt<<<2348, 256, 0, stream>>>(x, Wq, Wk, Wv, xb, Wt);
    gemm_qkv<<<960, 256, 0, stream>>>(xb, Wt, msk, QF, KF, VF, qs, km);
    attn_strip<<<2560, 256, 0, stream>>>(QF, KF, VF, qs, km, out);
}

// Round 11
// 78.045 us; speedup vs baseline: 1.0230x; 1.0145x over previous
//
#include <hip/hip_runtime.h>
#include <hip/hip_bf16.h>
#include <stdint.h>

// B=8, T=1024, D=U=640, H=10, d=64
#define B_DIM 8
#define T_DIM 1024
#define D_DIM 640
#define H_DIM 10
#define LOG2E 1.442695041f

typedef unsigned short ushort_t;
typedef __attribute__((ext_vector_type(8))) short short8;
typedef __attribute__((ext_vector_type(4))) float f32x4;
typedef __attribute__((ext_vector_type(16))) float f32x16;
typedef __attribute__((ext_vector_type(4))) unsigned int u32x4;

__device__ __forceinline__ ushort_t f32_to_bf16(float f) {
    unsigned int u = __builtin_bit_cast(unsigned int, f);
    u += 0x7fffu + ((u >> 16) & 1u);   // RNE
    return (ushort_t)(u >> 16);
}
__device__ __forceinline__ float v_exp2(float x) {
    float r; asm("v_exp_f32 %0, %1" : "=v"(r) : "v"(x)); return r;
}
__device__ __forceinline__ unsigned cvt_pk_bf16(float a, float b) {
    unsigned r; asm("v_cvt_pk_bf16_f32 %0, %1, %2" : "=v"(r) : "v"(a), "v"(b)); return r;
}
// async global->LDS (GEMM staging). Dest = wave-uniform base + lane*16.
__device__ __forceinline__ void gload16(const void* g, void* l) {
    auto gp = reinterpret_cast<const __attribute__((address_space(1))) uint32_t*>(
        reinterpret_cast<uintptr_t>(g));
    auto lp = reinterpret_cast<__attribute__((address_space(3))) uint32_t*>(
        reinterpret_cast<uintptr_t>(l));
    __builtin_amdgcn_global_load_lds(gp, lp, 16, 0, 0);
}

// strips sorted heavy-first by tile count: 0(16),31(16),30(16),29(15),...
__constant__ int SPERM[32] = {0,31,30,29,28,27,26,25,24,23,22,21,20,19,18,17,
                              16,15,14,13,12,11,10,9,8,7,6,5,4,3,2,1};

// ---------------------------------------------------------------------------
// Kernel A: fused { W transpose->bf16 (blocks 0..299) , x->bf16 (blocks 300+) }
// ---------------------------------------------------------------------------
__global__ __launch_bounds__(256) void convwt(
    const float* __restrict__ x,
    const float* __restrict__ Wq, const float* __restrict__ Wk, const float* __restrict__ Wv,
    ushort_t* __restrict__ xb, ushort_t* __restrict__ Wt)
{
    const int tid = threadIdx.x;
    if (blockIdx.x < 300) {
        const int w = blockIdx.x / 100, rem = blockIdx.x % 100;
        const int k0 = (rem % 10) * 64, n0 = (rem / 10) * 64;
        const float* W = (w == 0) ? Wq : (w == 1) ? Wk : Wv;
        ushort_t* Wo = Wt + (size_t)w * D_DIM * D_DIM;

        __shared__ alignas(16) ushort_t st[64][72];
        const int r = tid >> 2, cs = (tid & 3) * 16;
        #pragma unroll
        for (int j = 0; j < 4; ++j) {
            float4 v = *reinterpret_cast<const float4*>(
                &W[(size_t)(k0 + r) * D_DIM + n0 + cs + j * 4]);
            st[r][cs + j * 4 + 0] = f32_to_bf16(v.x);
            st[r][cs + j * 4 + 1] = f32_to_bf16(v.y);
            st[r][cs + j * 4 + 2] = f32_to_bf16(v.z);
            st[r][cs + j * 4 + 3] = f32_to_bf16(v.w);
        }
        __syncthreads();
        const int nr = tid >> 2, ks = (tid & 3) * 16;
        ushort_t tmp[16];
        #pragma unroll
        for (int j = 0; j < 16; ++j) tmp[j] = st[ks + j][nr];
        ushort_t* dst = &Wo[(size_t)(n0 + nr) * D_DIM + k0 + ks];
        *reinterpret_cast<short8*>(dst)     = *reinterpret_cast<const short8*>(&tmp[0]);
        *reinterpret_cast<short8*>(dst + 8) = *reinterpret_cast<const short8*>(&tmp[8]);
    } else {
        const int n8 = (B_DIM * T_DIM * D_DIM) / 8;
        for (int i = (blockIdx.x - 300) * 256 + tid; i < n8; i += 2048 * 256) {
            float4 a = *reinterpret_cast<const float4*>(&x[i * 8]);
            float4 b = *reinterpret_cast<const float4*>(&x[i * 8 + 4]);
            ushort_t o[8] = {f32_to_bf16(a.x), f32_to_bf16(a.y), f32_to_bf16(a.z), f32_to_bf16(a.w),
                             f32_to_bf16(b.x), f32_to_bf16(b.y), f32_to_bf16(b.z), f32_to_bf16(b.w)};
            *reinterpret_cast<short8*>(&xb[i * 8]) = *reinterpret_cast<const short8*>(o);
        }
    }
}

// ---------------------------------------------------------------------------
// Kernel B: bf16 MFMA GEMM, BK=32, double-buffered LDS + counted vmcnt + raw
// barriers (no per-iter vmcnt(0) drain). Outputs in 32x32x16 fragment layouts
// (same as before). Sign masks via ballot (16 ballots vs 64 shfls).
// ---------------------------------------------------------------------------
__global__ __launch_bounds__(256) void gemm_qkv(
    const ushort_t* __restrict__ xb, const ushort_t* __restrict__ Wt,
    const int* __restrict__ msk,
    ushort_t* __restrict__ QF, ushort_t* __restrict__ KF, ushort_t* __restrict__ VF,
    float* __restrict__ qs, ushort_t* __restrict__ km16)
{
    const int L = blockIdx.x;
    const int xcd = L & 7, j = L >> 3;
    const int m0 = (xcd * 8 + (j & 7)) * 128;
    const int nz = j >> 3;               // 0..14
    const int n0 = (nz % 5) * 128;
    const int w  = nz / 5;

    const ushort_t* Wm = Wt + (size_t)w * D_DIM * D_DIM;

    // 2 buffers x (128 rows x 32 cols) x 2 operands = 32 KB
    __shared__ alignas(16) ushort_t As[2][128 * 32];
    __shared__ alignas(16) ushort_t Bs[2][128 * 32];

    const int tid = threadIdx.x;
    const int lane = tid & 63, wave = tid >> 6;
    const int lo = lane & 15, g = lane >> 4;
    const int wm = wave >> 1, wn = wave & 1;

    f32x4 acc[4][4];
    #pragma unroll
    for (int i = 0; i < 4; ++i)
        #pragma unroll
        for (int jj = 0; jj < 4; ++jj) acc[i][jj] = (f32x4){0.f, 0.f, 0.f, 0.f};

    // stage one 128x32 A-tile + B-tile: 512 slots each, 2 gload16/thread/op.
    // slot -> row = slot>>2, chunk c = slot&3; source k-chunk sc = c ^ ((row>>1)&3)
#define GSTAGE(K0_, BUF_) do {                                                   \
        _Pragma("unroll")                                                        \
        for (int i_ = 0; i_ < 2; ++i_) {                                         \
            int slot_ = i_ * 256 + tid;                                          \
            int row_ = slot_ >> 2;                                               \
            int sc_ = (slot_ & 3) ^ ((row_ >> 1) & 3);                           \
            gload16(&xb[(size_t)(m0 + row_) * D_DIM + (K0_) + sc_ * 8],          \
                    &As[BUF_][slot_ * 8]);                                       \
            gload16(&Wm[(size_t)(n0 + row_) * D_DIM + (K0_) + sc_ * 8],          \
                    &Bs[BUF_][slot_ * 8]);                                       \
        }                                                                        \
    } while (0)

    GSTAGE(0, 0);
    int cur = 0;
    for (int it = 0; it < 20; ++it) {
        if (it < 19) {
            GSTAGE((it + 1) * 32, cur ^ 1);
            asm volatile("s_waitcnt vmcnt(4)" ::: "memory");  // current buf landed
        } else {
            asm volatile("s_waitcnt vmcnt(0)" ::: "memory");
        }
        __builtin_amdgcn_s_barrier();

        short8 af[4], bf[4];
        #pragma unroll
        for (int t = 0; t < 4; ++t) {
            int arow = wm * 64 + t * 16 + lo;
            int ach = g ^ ((arow >> 1) & 3);
            af[t] = *reinterpret_cast<const short8*>(&As[cur][(arow * 4 + ach) * 8]);
            int brow = wn * 64 + t * 16 + lo;
            int bch = g ^ ((brow >> 1) & 3);
            bf[t] = *reinterpret_cast<const short8*>(&Bs[cur][(brow * 4 + bch) * 8]);
        }
        __builtin_amdgcn_s_setprio(1);
        #pragma unroll
        for (int mi = 0; mi < 4; ++mi)
            #pragma unroll
            for (int ni = 0; ni < 4; ++ni)
                acc[mi][ni] = __builtin_amdgcn_mfma_f32_16x16x32_bf16(
                    af[mi], bf[ni], acc[mi][ni], 0, 0, 0);
        __builtin_amdgcn_s_setprio(0);
        __builtin_amdgcn_s_barrier();   // all reads of buf[cur] done
        cur ^= 1;
    }
#undef GSTAGE

    const int hh = (n0 >> 6) + wn;           // head 0..9 for this wave's half
    const int bb = m0 >> 10;                 // batch
    const int hb = hh * 8 + bb;
    const int ktw = ((m0 & 1023) >> 6) + wm; // 64-row tile index

    if (w == 2) {
        // V -> VF fragment layout; 4 consecutive keys pack into ushort4
        const int hiv = g >> 1, jj0 = (g & 1) * 4;
        #pragma unroll
        for (int mi = 0; mi < 4; ++mi)
            #pragma unroll
            for (int ni = 0; ni < 4; ++ni) {
                const int df = ni >> 1, l31v = (ni & 1) * 16 + lo;
                size_t idx = ((((size_t)(hb * 16 + ktw) * 4 + mi) * 2 + df) * 64
                              + hiv * 32 + l31v) * 8 + jj0;
                ushort4 o = make_ushort4(f32_to_bf16(acc[mi][ni][0]), f32_to_bf16(acc[mi][ni][1]),
                                         f32_to_bf16(acc[mi][ni][2]), f32_to_bf16(acc[mi][ni][3]));
                *reinterpret_cast<ushort4*>(&VF[idx]) = o;
            }
    } else {
        // sign masks: row-nonzero = OR over the 16 lanes holding the row
        // lanes g*16..g*16+15 of the ballot all share this row group
        #pragma unroll
        for (int mi = 0; mi < 4; ++mi)
            #pragma unroll
            for (int r = 0; r < 4; ++r) {
                float s_ = fabsf(acc[mi][0][r]) + fabsf(acc[mi][1][r])
                         + fabsf(acc[mi][2][r]) + fabsf(acc[mi][3][r]);
                unsigned long long bal = __ballot(s_ != 0.f);
                if (lo == 0) {
                    int row = m0 + wm * 64 + mi * 16 + g * 4 + r;
                    int rowid = hh * 8192 + row;
                    bool nz = ((bal >> (g * 16)) & 0xFFFFull) != 0ull;
                    if (w == 0) qs[rowid] = (nz ? 1.f : 0.f) * (float)msk[row];
                    else        km16[rowid] = nz ? (ushort_t)0x3F80 : (ushort_t)0;
                }
            }
        // fragment-layout stores
        const int hi2 = lo >> 3, jjq = lo & 7;
        const int s32base = ((m0 & 1023) + wm * 64) >> 5;
        #pragma unroll
        for (int mi = 0; mi < 4; ++mi)
            #pragma unroll
            for (int ni = 0; ni < 4; ++ni)
                #pragma unroll
                for (int r = 0; r < 4; ++r) {
                    int l31 = (mi & 1) * 16 + g * 4 + r;
                    if (w == 0) {
                        int s32 = s32base + (mi >> 1);
                        size_t idx = (((size_t)(hb * 32 + s32) * 4 + ni) * 64
                                      + hi2 * 32 + l31) * 8 + jjq;
                        QF[idx] = f32_to_bf16(acc[mi][ni][r]);
                    } else {
                        int f = (mi >> 1) & 1;
                        size_t idx = ((((size_t)(hb * 16 + ktw) * 2 + f) * 4 + ni) * 64
                                      + hi2 * 32 + l31) * 8 + jjq;
                        KF[idx] = f32_to_bf16(acc[mi][ni][r]);
                    }
                }
    }
}

// ---------------------------------------------------------------------------
// Kernel C: flash attention with 4-way k-split per strip (unchanged, round 10).
// ---------------------------------------------------------------------------
#define DO_TILE(KT_IDX) do {                                                     \
    const int k0_ = (KT_IDX) * 64;                                               \
    const ushort_t* KT_ = &KFh[(size_t)(KT_IDX) * 4096];                         \
    const ushort_t* VT_ = &VFh[(size_t)(KT_IDX) * 4096];                         \
    short8 kA_[2][4];                                                            \
    _Pragma("unroll")                                                            \
    for (int f_ = 0; f_ < 2; ++f_)                                               \
        _Pragma("unroll")                                                        \
        for (int kc_ = 0; kc_ < 4; ++kc_)                                        \
            kA_[f_][kc_] = *reinterpret_cast<const short8*>(                     \
                &KT_[(f_ * 4 + kc_) * 512 + lane * 8]);                          \
    short8 vfA_[2][2], vfB_[2][2];                                               \
    _Pragma("unroll")                                                            \
    for (int c_ = 0; c_ < 2; ++c_)                                               \
        _Pragma("unroll")                                                        \
        for (int df_ = 0; df_ < 2; ++df_)                                        \
            vfA_[c_][df_] = *reinterpret_cast<const short8*>(                    \
                &VT_[(c_ * 2 + df_) * 512 + lane * 8]);                          \
    ushort4 kq_[2][4];                                                           \
    _Pragma("unroll")                                                            \
    for (int f_ = 0; f_ < 2; ++f_)                                               \
        _Pragma("unroll")                                                        \
        for (int rr_ = 0; rr_ < 4; ++rr_)                                        \
            kq_[f_][rr_] = *reinterpret_cast<const ushort4*>(                    \
                &kmr[k0_ + f_ * 32 + rr_ * 8 + hi * 4]);                         \
    unsigned pk_[2][8];                                                          \
    _Pragma("unroll")                                                            \
    for (int f_ = 0; f_ < 2; ++f_) {                                             \
        f32x16 sf_;                                                              \
        _Pragma("unroll")                                                        \
        for (int i_ = 0; i_ < 16; ++i_) sf_[i_] = 0.f;                           \
        __builtin_amdgcn_s_setprio(1);                                           \
        _Pragma("unroll")                                                        \
        for (int kc_ = 0; kc_ < 4; ++kc_)                                        \
            sf_ = __builtin_amdgcn_mfma_f32_32x32x16_bf16(kA_[f_][kc_],          \
                                                          qf[kc_], sf_, 0, 0, 0);\
        __builtin_amdgcn_s_setprio(0);                                           \
        if (f_ == 0) {                                                           \
            _Pragma("unroll")                                                    \
            for (int c_ = 0; c_ < 2; ++c_)                                       \
                _Pragma("unroll")                                                \
                for (int df_ = 0; df_ < 2; ++df_)                                \
                    vfB_[c_][df_] = *reinterpret_cast<const short8*>(            \
                        &VT_[((c_ + 2) * 2 + df_) * 512 + lane * 8]);            \
        }                                                                        \
        _Pragma("unroll")                                                        \
        for (int rr_ = 0; rr_ < 4; ++rr_) {                                      \
            const int kbase_ = k0_ + f_ * 32 + rr_ * 8 + hi * 4;                 \
            const ushort_t* kmv_ =                                               \
                reinterpret_cast<const ushort_t*>(&kq_[f_][rr_]);                \
            float p_[4];                                                         \
            _Pragma("unroll")                                                    \
            for (int ri_ = 0; ri_ < 4; ++ri_) {                                  \
                float cc_ = (kbase_ + ri_ >= trow) ? cB : cA;                    \
                cc_ = kmv_[ri_] ? cc_ : -1e30f;                                  \
                p_[ri_] = v_exp2(fmaf(sf_[rr_ * 4 + ri_], S2, cc_));             \
                lacc += p_[ri_];                                                 \
            }                                                                    \
            pk_[f_][rr_ * 2 + 0] = cvt_pk_bf16(p_[0], p_[1]);                    \
            pk_[f_][rr_ * 2 + 1] = cvt_pk_bf16(p_[2], p_[3]);                    \
        }                                                                        \
    }                                                                            \
    _Pragma("unroll")                                                            \
    for (int c_ = 0; c_ < 4; ++c_) {                                             \
        const int f_ = c_ >> 1, o_ = (c_ & 1) * 4;                               \
        unsigned a0_ = pk_[f_][o_ + 0], b0_ = pk_[f_][o_ + 2];                   \
        unsigned a1_ = pk_[f_][o_ + 1], b1_ = pk_[f_][o_ + 3];                   \
        if (v1) {                                                                \
            asm volatile("v_permlane32_swap_b32 %0, %1" : "+v"(b0_), "+v"(a0_)); \
            asm volatile("v_permlane32_swap_b32 %0, %1" : "+v"(b1_), "+v"(a1_)); \
        } else {                                                                 \
            asm volatile("v_permlane32_swap_b32 %0, %1" : "+v"(a0_), "+v"(b0_)); \
            asm volatile("v_permlane32_swap_b32 %0, %1" : "+v"(a1_), "+v"(b1_)); \
        }                                                                        \
        u32x4 pau_ = {a0_, a1_, b0_, b1_};                                       \
        short8 pa_ = __builtin_bit_cast(short8, pau_);                           \
        short8 v0_ = (c_ < 2) ? vfA_[c_][0] : vfB_[c_ - 2][0];                   \
        short8 v1f_ = (c_ < 2) ? vfA_[c_][1] : vfB_[c_ - 2][1];                  \
        __builtin_amdgcn_s_setprio(1);                                           \
        of0 = __builtin_amdgcn_mfma_f32_32x32x16_bf16(pa_, v0_, of0, 0, 0, 0);   \
        of1 = __builtin_amdgcn_mfma_f32_32x32x16_bf16(pa_, v1f_, of1, 0, 0, 0);  \
        __builtin_amdgcn_s_setprio(0);                                           \
    }                                                                            \
} while (0)

__global__ __launch_bounds__(256, 3) void attn_strip(
    const ushort_t* __restrict__ QF, const ushort_t* __restrict__ KF,
    const ushort_t* __restrict__ VF, const float* __restrict__ qs,
    const ushort_t* __restrict__ km16, float* __restrict__ out)
{
    __shared__ alignas(16) float mrg[3 * 64 * 36];   // 27,648 B

    const int tid = threadIdx.x, lane = tid & 63, wave = tid >> 6;
    const int l31 = lane & 31, hi = lane >> 5;

    // mapping: block = (b,h, strip). same-(b,h) on one XCD; heavy strips first.
    const int bid = blockIdx.x;                 // 0..2559
    const int xcd = bid & 7, i = bid >> 3;      // i 0..319
    const int sr = i / 10, grp = i % 10;
    const int g8 = xcd + 8 * grp;               // (b,h) group 0..79
    const int s = SPERM[sr], q0 = s * 32;
    const int b = g8 & 7, h = g8 >> 3, hb = h * 8 + b;

    // --- probe permlane32_swap direction (HW variant), wave-uniform ---
    unsigned pva = (unsigned)lane, pvb = 64u + (unsigned)lane;
    asm volatile("v_permlane32_swap_b32 %0, %1" : "+v"(pva), "+v"(pvb));
    const bool v1 = (__builtin_amdgcn_readfirstlane((int)pva) >= 96);

    const ushort_t* QFh = QF + (size_t)(hb * 32 + s) * 2048;
    const ushort_t* KFh = KF + (size_t)hb * 16 * 4096;
    const ushort_t* VFh = VF + (size_t)hb * 16 * 4096;
    const ushort_t* kmr = km16 + (size_t)hb * 1024;

    // Q fragments (B-operand), loop-invariant; all 4 waves load same -> L1 hit
    short8 qf[4];
    #pragma unroll
    for (int kc = 0; kc < 4; ++kc)
        qf[kc] = *reinterpret_cast<const short8*>(&QFh[kc * 512 + lane * 8]);

    // per-row shift M: any unpadded key strictly before row q0+l31?
    bool anyPrior = false;
    for (int c = 0; c < (q0 >> 6); ++c) {
        ushort_t v = kmr[c * 64 + lane];
        anyPrior = anyPrior || (__ballot(v != 0) != 0ull);
    }
    float M;
    {
        ushort_t v = kmr[(q0 & ~63) + lane];
        unsigned long long bal = __ballot(v != 0);
        unsigned long long pre = bal & ((1ull << ((q0 & 63) + l31)) - 1ull);
        M = (anyPrior || pre != 0ull) ? 16.f : -9984.f;
    }
    const float cA = -M * LOG2E;
    const float cB = cA - 10000.0f * LOG2E;
    const float S2 = 0.125f * LOG2E;
    const int trow = q0 + l31;

    float lacc = 0.f;
    f32x16 of0, of1;
    #pragma unroll
    for (int i2 = 0; i2 < 16; ++i2) { of0[i2] = 0.f; of1[i2] = 0.f; }

    const int ktend = (s == 0) ? 16 : ((s >> 1) + 1);

    // wave's interleaved tile subset
    for (int kt = wave; kt < ktend; kt += 4)
        DO_TILE(kt);

    // ---- merge partials: waves 1..3 -> LDS, wave 0 sums ----
    if (wave != 0) {
        float* dst = &mrg[((wave - 1) * 64 + lane) * 36];
        #pragma unroll
        for (int q = 0; q < 4; ++q) {
            reinterpret_cast<float4*>(dst)[q] =
                make_float4(of0[q * 4 + 0], of0[q * 4 + 1], of0[q * 4 + 2], of0[q * 4 + 3]);
            reinterpret_cast<float4*>(dst)[4 + q] =
                make_float4(of1[q * 4 + 0], of1[q * 4 + 1], of1[q * 4 + 2], of1[q * 4 + 3]);
        }
        dst[32] = lacc;
    }
    __syncthreads();
    if (wave == 0) {
        #pragma unroll
        for (int w2 = 0; w2 < 3; ++w2) {
            const float* src = &mrg[(w2 * 64 + lane) * 36];
            #pragma unroll
            for (int q = 0; q < 4; ++q) {
                float4 t0 = reinterpret_cast<const float4*>(src)[q];
                of0[q * 4 + 0] += t0.x; of0[q * 4 + 1] += t0.y;
                of0[q * 4 + 2] += t0.z; of0[q * 4 + 3] += t0.w;
                float4 t1 = reinterpret_cast<const float4*>(src)[4 + q];
                of1[q * 4 + 0] += t1.x; of1[q * 4 + 1] += t1.y;
                of1[q * 4 + 2] += t1.z; of1[q * 4 + 3] += t1.w;
            }
            lacc += src[32];
        }
        float ltot = lacc + __shfl_xor(lacc, 32);
        float scale = qs[(size_t)hb * 1024 + q0 + l31] / ltot;   // lane l: row l31
        const size_t obase = ((size_t)b * T_DIM + q0) * D_DIM + h * 64;
        #pragma unroll
        for (int reg = 0; reg < 16; ++reg) {
            const int qrow = (reg & 3) + 8 * (reg >> 2) + 4 * hi;
            const float sc = __shfl(scale, qrow);
            out[obase + (size_t)qrow * D_DIM + l31]      = of0[reg] * sc;
            out[obase + (size_t)qrow * D_DIM + 32 + l31] = of1[reg] * sc;
        }
    }
}

// ---------------------------------------------------------------------------
extern "C" void kernel_launch(void* const* d_in, const int* in_sizes, int n_in,
                              void* d_out, int out_size, void* d_ws, size_t ws_size,
                              hipStream_t stream)
{
    const float* x   = (const float*)d_in[0];
    const int*   msk = (const int*)d_in[1];
    const float* Wq  = (const float*)d_in[2];
    const float* Wk  = (const float*)d_in[3];
    const float* Wv  = (const float*)d_in[4];
    float* out = (float*)d_out;

    // workspace layout (bytes)
    char* ws = (char*)d_ws;
    ushort_t* xb = (ushort_t*)(ws);                    // 10,485,760
    ushort_t* Wt = (ushort_t*)(ws + 10485760);         //  2,457,600
    ushort_t* QF = (ushort_t*)(ws + 12943360);         // 10,485,760
    ushort_t* KF = (ushort_t*)(ws + 23429120);         // 10,485,760
    ushort_t* VF = (ushort_t*)(ws + 33914880);         // 10,485,760
    float*    qs = (float*)(ws + 44400640);            //    327,680
    ushort_t* km = (ushort_t*)(ws + 44728320);         //    163,840
    if (ws_size < 44892160) return;

    convwt<<<2348, 256, 0, stream>>>(x, Wq, Wk, Wv, xb, Wt);
    gemm_qkv<<<960, 256, 0, stream>>>(xb, Wt, msk, QF, KF, VF, qs, km);
    attn_strip<<<2560, 256, 0, stream>>>(QF, KF, VF, qs, km, out);
}